// Round 4
// baseline (20069.060 us; speedup 1.0000x reference)
//
#include <hip/hip_runtime.h>

// ---------------------------------------------------------------------------
// Problem constants
// ---------------------------------------------------------------------------
static constexpr int LSEQ = 512;   // timesteps
static constexpr int NB   = 256;   // batch
static constexpr int CIN  = 256;   // input dim
static constexpr int HD   = 512;   // hidden dim
static constexpr int G3   = 1536;  // 3*HD
static constexpr int NOUT = 256;   // output dim

typedef __attribute__((ext_vector_type(8))) short bf16x8;
typedef __attribute__((ext_vector_type(4))) float f32x4;
typedef __attribute__((ext_vector_type(8))) unsigned short u16x8;

#define DEVI __device__ __forceinline__

DEVI float b2f(unsigned short h) { return __uint_as_float(((unsigned)h) << 16); }
DEVI unsigned short f2b(float x) {
    unsigned u = __float_as_uint(x);
    return (unsigned short)((u + 0x7FFFu + ((u >> 16) & 1u)) >> 16);
}

// Device-coherent dword access (LLC coherence point; safe across XCDs).
DEVI unsigned cload(const unsigned* p) {
    return __hip_atomic_load(p, __ATOMIC_RELAXED, __HIP_MEMORY_SCOPE_AGENT);
}
DEVI void cstore(unsigned* p, unsigned v) {
    __hip_atomic_store(p, v, __ATOMIC_RELAXED, __HIP_MEMORY_SCOPE_AGENT);
}

// ---------------------------------------------------------------------------
// Float-dtype detection: sample x as u16s. If data is f32, the low u16 of each
// float is random mantissa bits -> as a "bf16" its exponent field (bits 14:7)
// is uniform, hitting >=0xC0 (|v|>=2^65) ~25% of the time. Genuine bf16
// activations/weights (|v| < 100) never have exponent >= 0xC0.
// fdt = 1 -> inputs are f32; fdt = 0 -> inputs are bf16.
// ---------------------------------------------------------------------------
__global__ void detect_fdt(const unsigned short* __restrict__ x, int nHalf,
                           unsigned* __restrict__ fdt) {
    __shared__ unsigned big;
    if (threadIdx.x == 0) big = 0;
    __syncthreads();
    for (int i = threadIdx.x; i < nHalf; i += 256) {
        unsigned e = (x[i] >> 7) & 0xFFu;
        if (e >= 0xC0u) atomicOr(&big, 1u);
    }
    __syncthreads();
    if (threadIdx.x == 0) *fdt = big ? 1u : 0u;
}

// Cast a float tensor (f32 or bf16 per *fdt) to a bf16 staging buffer.
__global__ void cast_bf16(const void* __restrict__ src, long srcOff,
                          unsigned short* __restrict__ dst, long n,
                          const unsigned* __restrict__ fdt) {
    long i = (long)blockIdx.x * 256 + threadIdx.x;
    long stride = (long)gridDim.x * 256;
    if (*fdt) {
        const float* s = (const float*)src + srcOff;
        for (; i < n; i += stride) dst[i] = f2b(s[i]);
    } else {
        const unsigned short* s = (const unsigned short*)src + srcOff;
        for (; i < n; i += stride) dst[i] = s[i];
    }
}

// ---------------------------------------------------------------------------
// done-mask handling: runtime dtype detection (bool/int8 vs int32 vs bf16 vs f32)
// ---------------------------------------------------------------------------
__global__ void detect_done(const unsigned char* __restrict__ d, int elems,
                            unsigned* __restrict__ flag) {
    __shared__ unsigned bad[4];
    int tid = threadIdx.x;
    if (tid < 4) bad[tid] = 0;
    __syncthreads();
    int nInt = elems >> 2;  // reads at most `elems` bytes under every layout
    const unsigned* di = (const unsigned*)d;
    for (int i = tid; i < nInt; i += 256) {
        unsigned v = di[i];
        if (v > 1u) atomicOr(&bad[0], 1u);
        if (v != 0u && v != 0x3F800000u) atomicOr(&bad[1], 1u);
    }
    int nHalf = elems >> 1;
    const unsigned short* dh = (const unsigned short*)d;
    for (int i = tid; i < nHalf; i += 256) {
        unsigned short h = dh[i];
        if (h != 0 && h != 0x3F80) atomicOr(&bad[2], 1u);
    }
    __syncthreads();
    if (tid == 0) {
        unsigned f;
        if (!bad[0]) f = 0u;       // int32 0/1
        else if (!bad[1]) f = 3u;  // float32
        else if (!bad[2]) f = 2u;  // bf16
        else f = 1u;               // bytes (bool / int8)
        *flag = f;
    }
}

__global__ void expand_done(const void* __restrict__ d, const unsigned* __restrict__ flag,
                            float* __restrict__ keep, int elems) {
    int i = blockIdx.x * 256 + threadIdx.x;
    if (i >= elems) return;
    unsigned f = *flag;
    float v;
    if (f == 0u)      v = (float)((const int*)d)[i];
    else if (f == 1u) v = (float)((const unsigned char*)d)[i];
    else if (f == 2u) v = b2f(((const unsigned short*)d)[i]);
    else              v = ((const float*)d)[i];
    keep[i] = 1.f - v;
}

// ---------------------------------------------------------------------------
// NT GEMM: C[M,N] = A[M,K] @ B[N,K]^T + bias, bf16 in, f32 accum.
// m97-style: 128x128 tile, BK=64, 4 waves, 16x16x32 MFMA, global_load_lds.
// Output: bf16 to C (LDS-staged coalesced) OR f32 to Cf when *fdt!=0.
// ---------------------------------------------------------------------------
__global__ __launch_bounds__(256) void gemm_nt(
    const unsigned short* __restrict__ A, const unsigned short* __restrict__ B,
    const unsigned short* __restrict__ bias, unsigned short* __restrict__ C,
    float* __restrict__ Cf, const unsigned* __restrict__ fdt,
    int M, int N, int K) {
    __shared__ unsigned short sm[16384];  // A: [0,8192), B: [8192,16384)
    const int tid = threadIdx.x;
    const int l = tid & 63, w = tid >> 6;
    const int lr = l & 15, lq = l >> 4;
    const int wr = w >> 1, wc = w & 1;
    const long rowBase = (long)blockIdx.y * 128;
    const long colBase = (long)blockIdx.x * 128;

    int qrow[4], qc8[4];
#pragma unroll
    for (int i = 0; i < 4; i++) {
        int q = (i * 4 + w) * 64 + l;  // 16B-chunk id within the 128x64 tile
        qrow[i] = q >> 3;
        qc8[i] = (q & 7) * 8;
    }

    f32x4 acc[4][4] = {};

    for (int k0 = 0; k0 < K; k0 += 64) {
#pragma unroll
        for (int i = 0; i < 4; i++) {
            const unsigned short* sA = A + (rowBase + qrow[i]) * K + k0 + qc8[i];
            const unsigned short* sB = B + (colBase + qrow[i]) * K + k0 + qc8[i];
            __builtin_amdgcn_global_load_lds(
                (const __attribute__((address_space(1))) void*)sA,
                (__attribute__((address_space(3))) void*)(sm + (i * 4 + w) * 512), 16, 0, 0);
            __builtin_amdgcn_global_load_lds(
                (const __attribute__((address_space(1))) void*)sB,
                (__attribute__((address_space(3))) void*)(sm + 8192 + (i * 4 + w) * 512), 16, 0, 0);
        }
        __syncthreads();
#pragma unroll
        for (int ks = 0; ks < 2; ks++) {
            bf16x8 af[4], bfr[4];
#pragma unroll
            for (int mi = 0; mi < 4; mi++)
                af[mi] = *(const bf16x8*)&sm[(wr * 64 + mi * 16 + lr) * 64 + ks * 32 + lq * 8];
#pragma unroll
            for (int ni = 0; ni < 4; ni++)
                bfr[ni] = *(const bf16x8*)&sm[8192 + (wc * 64 + ni * 16 + lr) * 64 + ks * 32 + lq * 8];
#pragma unroll
            for (int mi = 0; mi < 4; mi++)
#pragma unroll
                for (int ni = 0; ni < 4; ni++)
                    acc[mi][ni] = __builtin_amdgcn_mfma_f32_16x16x32_bf16(
                        af[mi], bfr[ni], acc[mi][ni], 0, 0, 0);
        }
        __syncthreads();
    }

    float bv[4];
#pragma unroll
    for (int ni = 0; ni < 4; ni++)
        bv[ni] = bias ? b2f(bias[colBase + wc * 64 + ni * 16 + lr]) : 0.f;

    const bool f32out = (fdt != nullptr) && (*fdt != 0u);
    if (f32out) {
        // direct f32 scatter stores (16-col = 64B contiguous runs; fine for the
        // single projection GEMM)
#pragma unroll
        for (int mi = 0; mi < 4; mi++)
#pragma unroll
            for (int ni = 0; ni < 4; ni++)
#pragma unroll
                for (int rg = 0; rg < 4; rg++) {
                    int m = wr * 64 + mi * 16 + lq * 4 + rg;
                    int n = wc * 64 + ni * 16 + lr;
                    Cf[(rowBase + m) * (long)N + colBase + n] = acc[mi][ni][rg] + bv[ni];
                }
        return;
    }

    // stage C tile (bf16) in LDS for coalesced 16B stores
#pragma unroll
    for (int mi = 0; mi < 4; mi++)
#pragma unroll
        for (int ni = 0; ni < 4; ni++)
#pragma unroll
            for (int rg = 0; rg < 4; rg++) {
                int m = wr * 64 + mi * 16 + lq * 4 + rg;
                int n = wc * 64 + ni * 16 + lr;
                sm[m * 128 + n] = f2b(acc[mi][ni][rg] + bv[ni]);
            }
    __syncthreads();
#pragma unroll
    for (int i = 0; i < 8; i++) {
        int idx = i * 2048 + tid * 8;
        int r = idx >> 7, c = idx & 127;
        *(u16x8*)(C + (rowBase + r) * N + colBase + c) = *(const u16x8*)&sm[idx];
    }
}

// ---------------------------------------------------------------------------
// GRU recurrence. Grid = 256 blocks x 256 threads.
//   bi = blockIdx.x & 15 -> batch rows [bi*16, +16); bj = blockIdx.x >> 4 ->
//   hidden cols [bj*32, +32). Whh fragment-resident in registers; K split
//   across 4 waves, partials reduced via padded LDS. Only the 16 blocks
//   sharing bi couple step-to-step -> 16-block group barrier (unique slot per
//   step). Cross-block h traffic is device-coherent (cload/cstore).
// ---------------------------------------------------------------------------
DEVI void groupbar(unsigned* wptr) {
    __syncthreads();  // drains this block's coherent stores before arrive
    if (threadIdx.x == 0) {
        __threadfence();
        __hip_atomic_fetch_add(wptr, 1u, __ATOMIC_ACQ_REL, __HIP_MEMORY_SCOPE_AGENT);
        while (__hip_atomic_load(wptr, __ATOMIC_ACQUIRE, __HIP_MEMORY_SCOPE_AGENT) < 16u)
            __builtin_amdgcn_s_sleep(2);
        __threadfence();
    }
    __syncthreads();
}

__global__ __launch_bounds__(256, 1) void gru_rec(
    const unsigned short* __restrict__ gi,   // [Tc][NB][G3] bf16 (bih folded in)
    const unsigned short* __restrict__ Whh,  // [G3][HD] bf16 (staged)
    const unsigned short* __restrict__ bhh,  // [G3] bf16 (staged)
    const float* __restrict__ keep,          // [LSEQ][NB]
    const unsigned short* __restrict__ mem,  // [NB][1024] bf16 (staged)
    unsigned short* __restrict__ hdb,        // [2][NB][HD] double buffer
    unsigned short* __restrict__ Y,          // [Tc][NB][HD] chunk-local bf16
    unsigned short* __restrict__ hnB,        // [NB][1024] bf16 out
    float* __restrict__ hnF,                 // [NB][1024] f32 out
    const unsigned* __restrict__ fdt,
    int t0, int Tc, int layerOff,
    unsigned* __restrict__ ctr) {            // (Tc+1)*16 slots, 32-word stride
    const int tid = threadIdx.x;
    const int l = tid & 63, w = tid >> 6, lr = l & 15, lq = l >> 4;
    const int bi = blockIdx.x & 15, bj = blockIdx.x >> 4;
    const bool f32out = (*fdt != 0u);

    __shared__ float red[4][16][100];  // padded stride

    // --- Whh fragments -> registers (one-time) ---
    bf16x8 wreg[6][4];
#pragma unroll
    for (int fr = 0; fr < 6; fr++) {
        int g = fr >> 1, cf = fr & 1;
        long row = (long)g * HD + bj * 32 + cf * 16 + lr;
#pragma unroll
        for (int ks = 0; ks < 4; ks++) {
            int k = w * 128 + ks * 32 + lq * 8;
            wreg[fr][ks] = *(const bf16x8*)(Whh + row * HD + k);
        }
    }

    const int m = tid >> 4, c0 = (tid & 15) * 2;
    const int n_g = bi * 16 + m;
    const int ch = bj * 32 + c0;
    float bh[3][2];
#pragma unroll
    for (int g = 0; g < 3; g++) {
        unsigned v = *(const unsigned*)(bhh + g * HD + ch);
        bh[g][0] = b2f((unsigned short)(v & 0xffffu));
        bh[g][1] = b2f((unsigned short)(v >> 16));
    }

    if (t0 == 0) {  // init h0 from memory (layer slice) into parity 0
        unsigned v = *(const unsigned*)(mem + (long)n_g * 1024 + layerOff + ch);
        cstore((unsigned*)(hdb + (long)n_g * HD + ch), v);
        groupbar(ctr + ((long)Tc * 16 + bi) * 32);
    }

    // prefetch gi/keep for first step
    unsigned gv[3];
    float kp;
    {
        const unsigned short* gp = gi + (long)n_g * G3;
#pragma unroll
        for (int g = 0; g < 3; g++) gv[g] = *(const unsigned*)(gp + g * HD + ch);
        kp = keep[(long)t0 * NB + n_g];
    }

    for (int t = t0; t < t0 + Tc; ++t) {
        const unsigned short* hc = hdb + (long)(t & 1) * NB * HD;
        unsigned short* hx = hdb + (long)((t + 1) & 1) * NB * HD;

        // coherent loads of the h stripe (written by the other 15 blocks)
        bf16x8 af[4];
        const unsigned* hrow = (const unsigned*)(hc + (long)(bi * 16 + lr) * HD);
#pragma unroll
        for (int ks = 0; ks < 4; ks++) {
            int dbase = w * 64 + ks * 16 + lq * 4;
            union { unsigned u[4]; bf16x8 v; } tmp;
#pragma unroll
            for (int q = 0; q < 4; q++) tmp.u[q] = cload(hrow + dbase + q);
            af[ks] = tmp.v;
        }
        unsigned hp = cload((const unsigned*)(hc + (long)n_g * HD + ch));

        f32x4 acc[6] = {};
#pragma unroll
        for (int ks = 0; ks < 4; ks++)
#pragma unroll
            for (int fr = 0; fr < 6; fr++)
                acc[fr] = __builtin_amdgcn_mfma_f32_16x16x32_bf16(af[ks], wreg[fr][ks], acc[fr], 0, 0, 0);

#pragma unroll
        for (int fr = 0; fr < 6; fr++)
#pragma unroll
            for (int rg = 0; rg < 4; rg++)
                red[w][lq * 4 + rg][fr * 16 + lr] = acc[fr][rg];
        __syncthreads();

        float s[3][2];
#pragma unroll
        for (int g = 0; g < 3; g++) { s[g][0] = 0.f; s[g][1] = 0.f; }
#pragma unroll
        for (int ww = 0; ww < 4; ww++)
#pragma unroll
            for (int g = 0; g < 3; g++) {
                const float* p = &red[ww][m][g * 32 + c0];
                s[g][0] += p[0];
                s[g][1] += p[1];
            }

        float hpv[2] = { b2f((unsigned short)(hp & 0xffffu)), b2f((unsigned short)(hp >> 16)) };
        unsigned short yo[2], ho[2];
        float hcf[2];
#pragma unroll
        for (int j = 0; j < 2; j++) {
            float ir  = b2f((unsigned short)((gv[0] >> (16 * j)) & 0xffffu));
            float iz  = b2f((unsigned short)((gv[1] >> (16 * j)) & 0xffffu));
            float in_ = b2f((unsigned short)((gv[2] >> (16 * j)) & 0xffffu));
            float r = 1.f / (1.f + __expf(-(ir + s[0][j] + bh[0][j])));
            float z = 1.f / (1.f + __expf(-(iz + s[1][j] + bh[1][j])));
            float nn = tanhf(in_ + r * (s[2][j] + bh[2][j]));
            float hnew = (1.f - z) * nn + z * hpv[j];
            hcf[j] = hnew * kp;
            yo[j] = f2b(hnew);
            ho[j] = f2b(hcf[j]);
        }
        unsigned ypack = (unsigned)yo[0] | ((unsigned)yo[1] << 16);
        unsigned hpack = (unsigned)ho[0] | ((unsigned)ho[1] << 16);
        *(unsigned*)(Y + ((long)(t - t0) * NB + n_g) * HD + ch) = ypack;   // cross-kernel
        cstore((unsigned*)(hx + (long)n_g * HD + ch), hpack);              // cross-block
        if (t == LSEQ - 1) {
            if (f32out) {
                hnF[(long)n_g * 1024 + layerOff + ch]     = hcf[0];
                hnF[(long)n_g * 1024 + layerOff + ch + 1] = hcf[1];
            } else {
                *(unsigned*)(hnB + (long)n_g * 1024 + layerOff + ch) = hpack;
            }
        }

        if (t + 1 < t0 + Tc) {
            const unsigned short* gp = gi + ((long)(t + 1 - t0) * NB + n_g) * G3;
#pragma unroll
            for (int g = 0; g < 3; g++) gv[g] = *(const unsigned*)(gp + g * HD + ch);
            kp = keep[(long)(t + 1) * NB + n_g];
            groupbar(ctr + ((long)(t - t0) * 16 + bi) * 32);
        }
    }
}

// ---------------------------------------------------------------------------
// Host launcher — dtype-adaptive chunked two-layer pipeline.
// Per chunk: cast(x)->XC, GEMM(XC)->GI, gru0->Y0c, GEMM(Y0c)->GI, gru1->Y1c,
//            GEMM(Y1c)->out chunk (dtype-switched epilogue).
// ---------------------------------------------------------------------------
extern "C" void kernel_launch(void* const* d_in, const int* in_sizes, int n_in,
                              void* d_out, int out_size, void* d_ws, size_t ws_size,
                              hipStream_t stream) {
    const void* x    = d_in[0];
    const void* mem  = d_in[1];
    const void* done = d_in[2];
    // float inputs to stage (device dtype unknown until detect_fdt runs)
    const void* fsrc[11] = { mem, d_in[3], d_in[4], d_in[5], d_in[6],
                             d_in[7], d_in[8], d_in[9], d_in[10], d_in[11], d_in[12] };
    const long  fn[11]   = { (long)NB * 1024, (long)G3 * CIN, (long)G3 * HD, G3, G3,
                             (long)G3 * HD, (long)G3 * HD, G3, G3, (long)NOUT * HD, NOUT };

    unsigned short* outB = (unsigned short*)d_out;
    float*          outF = (float*)d_out;
    unsigned short* hnB  = outB + (size_t)LSEQ * NB * NOUT;
    float*          hnF  = outF + (size_t)LSEQ * NB * NOUT;

    char* ws = (char*)d_ws;
    const size_t oFlag = 0;                                   // 256 B (fdt @ +0, done-flag @ +64)
    const size_t oKeep = 256;                                 // 0.5 MB
    const size_t oCtr  = oKeep + (size_t)LSEQ * NB * 4;       // 4 MB
    const size_t oWC   = oCtr + (size_t)4 * 1024 * 1024;      // 6.31 MB staged weights/mem
    size_t wcTot = 0;
    size_t wcOff[11];
    for (int i = 0; i < 11; i++) { wcOff[i] = wcTot; wcTot += (size_t)fn[i] * 2; wcTot = (wcTot + 255) & ~(size_t)255; }
    const size_t oHdb0 = oWC + wcTot;
    const size_t oHdb1 = oHdb0 + (size_t)2 * NB * HD * 2;
    const size_t oDyn  = oHdb1 + (size_t)2 * NB * HD * 2;

    int Tc = 4;
    const int cand[6] = {128, 64, 32, 16, 8, 4};
    for (int i = 0; i < 6; i++) {
        size_t need = oDyn + (size_t)cand[i] * NB * (CIN + G3 + 2 * HD) * 2;
        if (need <= ws_size) { Tc = cand[i]; break; }
    }
    const size_t oXC  = oDyn;
    const size_t oGI  = oXC + (size_t)Tc * NB * CIN * 2;
    const size_t oY0c = oGI + (size_t)Tc * NB * G3 * 2;
    const size_t oY1c = oY0c + (size_t)Tc * NB * HD * 2;

    unsigned*       FDT  = (unsigned*)(ws + oFlag);
    unsigned*       DFLG = (unsigned*)(ws + oFlag + 64);
    float*          KEEP = (float*)(ws + oKeep);
    unsigned*       CTR  = (unsigned*)(ws + oCtr);
    unsigned short* WC   = (unsigned short*)(ws + oWC);
    unsigned short* HDB0 = (unsigned short*)(ws + oHdb0);
    unsigned short* HDB1 = (unsigned short*)(ws + oHdb1);
    unsigned short* XC   = (unsigned short*)(ws + oXC);
    unsigned short* GIb  = (unsigned short*)(ws + oGI);
    unsigned short* Y0c  = (unsigned short*)(ws + oY0c);
    unsigned short* Y1c  = (unsigned short*)(ws + oY1c);

    unsigned short* MEMc = WC + wcOff[0] / 2;
    unsigned short* WIH0 = WC + wcOff[1] / 2;
    unsigned short* WHH0 = WC + wcOff[2] / 2;
    unsigned short* BIH0 = WC + wcOff[3] / 2;
    unsigned short* BHH0 = WC + wcOff[4] / 2;
    unsigned short* WIH1 = WC + wcOff[5] / 2;
    unsigned short* WHH1 = WC + wcOff[6] / 2;
    unsigned short* BIH1 = WC + wcOff[7] / 2;
    unsigned short* BHH1 = WC + wcOff[8] / 2;
    unsigned short* WPc  = WC + wcOff[9] / 2;
    unsigned short* BPc  = WC + wcOff[10] / 2;

    hipMemsetAsync(ws + oCtr, 0, (size_t)4 * 1024 * 1024, stream);
    detect_fdt<<<1, 256, 0, stream>>>((const unsigned short*)x, 4096, FDT);
    detect_done<<<1, 256, 0, stream>>>((const unsigned char*)done, in_sizes[2], DFLG);
    expand_done<<<(LSEQ * NB + 255) / 256, 256, 0, stream>>>(done, DFLG, KEEP, LSEQ * NB);

    // stage weights + memory as bf16
    for (int i = 0; i < 11; i++) {
        int blocks = (int)((fn[i] + 1023) / 1024);
        if (blocks > 2048) blocks = 2048;
        cast_bf16<<<blocks, 256, 0, stream>>>(fsrc[i], 0, WC + wcOff[i] / 2, fn[i], FDT);
    }

    size_t ctrWords = 0;
    const size_t ctrStep = (size_t)(Tc + 1) * 16 * 32;
    for (int t0 = 0; t0 < LSEQ; t0 += Tc) {
        const long xcN = (long)Tc * NB * CIN;
        cast_bf16<<<2048, 256, 0, stream>>>(x, (long)t0 * NB * CIN, XC, xcN, FDT);
        // layer 0 input GEMM: GI = x_chunk @ Wih0^T + bih0 (bf16 out)
        gemm_nt<<<dim3(G3 / 128, Tc * NB / 128), 256, 0, stream>>>(
            XC, WIH0, BIH0, GIb, nullptr, nullptr, Tc * NB, G3, CIN);
        gru_rec<<<256, 256, 0, stream>>>(GIb, WHH0, BHH0, KEEP, MEMc, HDB0,
                                         Y0c, hnB, hnF, FDT, t0, Tc, 0, CTR + ctrWords);
        ctrWords += ctrStep;
        // layer 1 input GEMM: GI = Y0c @ Wih1^T + bih1 (bf16 out)
        gemm_nt<<<dim3(G3 / 128, Tc * NB / 128), 256, 0, stream>>>(
            Y0c, WIH1, BIH1, GIb, nullptr, nullptr, Tc * NB, G3, HD);
        gru_rec<<<256, 256, 0, stream>>>(GIb, WHH1, BHH1, KEEP, MEMc, HDB1,
                                         Y1c, hnB, hnF, FDT, t0, Tc, HD, CTR + ctrWords);
        ctrWords += ctrStep;
        // projection: out_chunk = Y1c @ Wp^T + bp (dtype-switched epilogue)
        gemm_nt<<<dim3(NOUT / 128, Tc * NB / 128), 256, 0, stream>>>(
            Y1c, WPc, BPc, outB + (size_t)t0 * NB * NOUT,
            outF + (size_t)t0 * NB * NOUT, FDT, Tc * NB, NOUT, HD);
    }
}

// Round 5
// 3260.245 us; speedup vs baseline: 6.1557x; 6.1557x over previous
//
#include <hip/hip_runtime.h>

// ---------------------------------------------------------------------------
// Problem constants
// ---------------------------------------------------------------------------
static constexpr int LSEQ = 512;   // timesteps
static constexpr int NB   = 256;   // batch
static constexpr int CIN  = 256;   // input dim
static constexpr int HD   = 512;   // hidden dim
static constexpr int G3   = 1536;  // 3*HD
static constexpr int NOUT = 256;   // output dim

typedef __attribute__((ext_vector_type(8))) short bf16x8;
typedef __attribute__((ext_vector_type(4))) float f32x4;
typedef __attribute__((ext_vector_type(8))) unsigned short u16x8;
typedef __attribute__((ext_vector_type(4))) unsigned u32x4;

#define DEVI __device__ __forceinline__

DEVI float b2f(unsigned short h) { return __uint_as_float(((unsigned)h) << 16); }
DEVI unsigned short f2b(float x) {
    unsigned u = __float_as_uint(x);
    return (unsigned short)((u + 0x7FFFu + ((u >> 16) & 1u)) >> 16);
}

// Device-coherent dword access (LLC coherence point; safe across XCDs).
DEVI unsigned cload(const unsigned* p) {
    return __hip_atomic_load(p, __ATOMIC_RELAXED, __HIP_MEMORY_SCOPE_AGENT);
}
DEVI void cstore(unsigned* p, unsigned v) {
    __hip_atomic_store(p, v, __ATOMIC_RELAXED, __HIP_MEMORY_SCOPE_AGENT);
}

// 4x coherent 16B loads (LLC), one waitcnt. sched_barrier guards against the
// compiler hoisting register-only consumers past the inline-asm waitcnt
// (cdna_hip_programming rule #18).
DEVI void cload4x4(const unsigned* p0, const unsigned* p1,
                   const unsigned* p2, const unsigned* p3,
                   u32x4& r0, u32x4& r1, u32x4& r2, u32x4& r3) {
    asm volatile(
        "global_load_dwordx4 %0, %4, off sc0 sc1\n\t"
        "global_load_dwordx4 %1, %5, off sc0 sc1\n\t"
        "global_load_dwordx4 %2, %6, off sc0 sc1\n\t"
        "global_load_dwordx4 %3, %7, off sc0 sc1\n\t"
        "s_waitcnt vmcnt(0)"
        : "=&v"(r0), "=&v"(r1), "=&v"(r2), "=&v"(r3)
        : "v"(p0), "v"(p1), "v"(p2), "v"(p3)
        : "memory");
    __builtin_amdgcn_sched_barrier(0);
}

// ---------------------------------------------------------------------------
// Float-dtype detection: if data is f32, the low u16 of each float is random
// mantissa bits -> "bf16" exponent field >= 0xC0 (|v|>=2^65) ~25% of the time.
// Genuine bf16 activations/weights never have exponent >= 0xC0.
// ---------------------------------------------------------------------------
__global__ void detect_fdt(const unsigned short* __restrict__ x, int nHalf,
                           unsigned* __restrict__ fdt) {
    __shared__ unsigned big;
    if (threadIdx.x == 0) big = 0;
    __syncthreads();
    for (int i = threadIdx.x; i < nHalf; i += 256) {
        unsigned e = (x[i] >> 7) & 0xFFu;
        if (e >= 0xC0u) atomicOr(&big, 1u);
    }
    __syncthreads();
    if (threadIdx.x == 0) *fdt = big ? 1u : 0u;
}

// Cast a float tensor (f32 or bf16 per *fdt) to a bf16 staging buffer.
__global__ void cast_bf16(const void* __restrict__ src, long srcOff,
                          unsigned short* __restrict__ dst, long n,
                          const unsigned* __restrict__ fdt) {
    long i = (long)blockIdx.x * 256 + threadIdx.x;
    long stride = (long)gridDim.x * 256;
    if (*fdt) {
        const float* s = (const float*)src + srcOff;
        for (; i < n; i += stride) dst[i] = f2b(s[i]);
    } else {
        const unsigned short* s = (const unsigned short*)src + srcOff;
        for (; i < n; i += stride) dst[i] = s[i];
    }
}

// ---------------------------------------------------------------------------
// done-mask dtype detection (bool/int8 vs int32 vs bf16 vs f32)
// ---------------------------------------------------------------------------
__global__ void detect_done(const unsigned char* __restrict__ d, int elems,
                            unsigned* __restrict__ flag) {
    __shared__ unsigned bad[4];
    int tid = threadIdx.x;
    if (tid < 4) bad[tid] = 0;
    __syncthreads();
    int nInt = elems >> 2;
    const unsigned* di = (const unsigned*)d;
    for (int i = tid; i < nInt; i += 256) {
        unsigned v = di[i];
        if (v > 1u) atomicOr(&bad[0], 1u);
        if (v != 0u && v != 0x3F800000u) atomicOr(&bad[1], 1u);
    }
    int nHalf = elems >> 1;
    const unsigned short* dh = (const unsigned short*)d;
    for (int i = tid; i < nHalf; i += 256) {
        unsigned short h = dh[i];
        if (h != 0 && h != 0x3F80) atomicOr(&bad[2], 1u);
    }
    __syncthreads();
    if (tid == 0) {
        unsigned f;
        if (!bad[0]) f = 0u;       // int32 0/1
        else if (!bad[1]) f = 3u;  // float32
        else if (!bad[2]) f = 2u;  // bf16
        else f = 1u;               // bytes (bool / int8)
        *flag = f;
    }
}

__global__ void expand_done(const void* __restrict__ d, const unsigned* __restrict__ flag,
                            float* __restrict__ keep, int elems) {
    int i = blockIdx.x * 256 + threadIdx.x;
    if (i >= elems) return;
    unsigned f = *flag;
    float v;
    if (f == 0u)      v = (float)((const int*)d)[i];
    else if (f == 1u) v = (float)((const unsigned char*)d)[i];
    else if (f == 2u) v = b2f(((const unsigned short*)d)[i]);
    else              v = ((const float*)d)[i];
    keep[i] = 1.f - v;
}

// ---------------------------------------------------------------------------
// NT GEMM: C[M,N] = A[M,K] @ B[N,K]^T + bias, bf16 in, f32 accum.
// m97-style: 128x128 tile, BK=64, 4 waves, 16x16x32 MFMA, global_load_lds.
// Output: bf16 to C (LDS-staged coalesced) OR f32 to Cf when *fdt!=0.
// ---------------------------------------------------------------------------
__global__ __launch_bounds__(256) void gemm_nt(
    const unsigned short* __restrict__ A, const unsigned short* __restrict__ B,
    const unsigned short* __restrict__ bias, unsigned short* __restrict__ C,
    float* __restrict__ Cf, const unsigned* __restrict__ fdt,
    int M, int N, int K) {
    __shared__ unsigned short sm[16384];  // A: [0,8192), B: [8192,16384)
    const int tid = threadIdx.x;
    const int l = tid & 63, w = tid >> 6;
    const int lr = l & 15, lq = l >> 4;
    const int wr = w >> 1, wc = w & 1;
    const long rowBase = (long)blockIdx.y * 128;
    const long colBase = (long)blockIdx.x * 128;

    int qrow[4], qc8[4];
#pragma unroll
    for (int i = 0; i < 4; i++) {
        int q = (i * 4 + w) * 64 + l;  // 16B-chunk id within the 128x64 tile
        qrow[i] = q >> 3;
        qc8[i] = (q & 7) * 8;
    }

    f32x4 acc[4][4] = {};

    for (int k0 = 0; k0 < K; k0 += 64) {
#pragma unroll
        for (int i = 0; i < 4; i++) {
            const unsigned short* sA = A + (rowBase + qrow[i]) * K + k0 + qc8[i];
            const unsigned short* sB = B + (colBase + qrow[i]) * K + k0 + qc8[i];
            __builtin_amdgcn_global_load_lds(
                (const __attribute__((address_space(1))) void*)sA,
                (__attribute__((address_space(3))) void*)(sm + (i * 4 + w) * 512), 16, 0, 0);
            __builtin_amdgcn_global_load_lds(
                (const __attribute__((address_space(1))) void*)sB,
                (__attribute__((address_space(3))) void*)(sm + 8192 + (i * 4 + w) * 512), 16, 0, 0);
        }
        __syncthreads();
#pragma unroll
        for (int ks = 0; ks < 2; ks++) {
            bf16x8 af[4], bfr[4];
#pragma unroll
            for (int mi = 0; mi < 4; mi++)
                af[mi] = *(const bf16x8*)&sm[(wr * 64 + mi * 16 + lr) * 64 + ks * 32 + lq * 8];
#pragma unroll
            for (int ni = 0; ni < 4; ni++)
                bfr[ni] = *(const bf16x8*)&sm[8192 + (wc * 64 + ni * 16 + lr) * 64 + ks * 32 + lq * 8];
#pragma unroll
            for (int mi = 0; mi < 4; mi++)
#pragma unroll
                for (int ni = 0; ni < 4; ni++)
                    acc[mi][ni] = __builtin_amdgcn_mfma_f32_16x16x32_bf16(
                        af[mi], bfr[ni], acc[mi][ni], 0, 0, 0);
        }
        __syncthreads();
    }

    float bv[4];
#pragma unroll
    for (int ni = 0; ni < 4; ni++)
        bv[ni] = bias ? b2f(bias[colBase + wc * 64 + ni * 16 + lr]) : 0.f;

    const bool f32out = (fdt != nullptr) && (*fdt != 0u);
    if (f32out) {
#pragma unroll
        for (int mi = 0; mi < 4; mi++)
#pragma unroll
            for (int ni = 0; ni < 4; ni++)
#pragma unroll
                for (int rg = 0; rg < 4; rg++) {
                    int m = wr * 64 + mi * 16 + lq * 4 + rg;
                    int n = wc * 64 + ni * 16 + lr;
                    Cf[(rowBase + m) * (long)N + colBase + n] = acc[mi][ni][rg] + bv[ni];
                }
        return;
    }

    // stage C tile (bf16) in LDS for coalesced 16B stores
#pragma unroll
    for (int mi = 0; mi < 4; mi++)
#pragma unroll
        for (int ni = 0; ni < 4; ni++)
#pragma unroll
            for (int rg = 0; rg < 4; rg++) {
                int m = wr * 64 + mi * 16 + lq * 4 + rg;
                int n = wc * 64 + ni * 16 + lr;
                sm[m * 128 + n] = f2b(acc[mi][ni][rg] + bv[ni]);
            }
    __syncthreads();
#pragma unroll
    for (int i = 0; i < 8; i++) {
        int idx = i * 2048 + tid * 8;
        int r = idx >> 7, c = idx & 127;
        *(u16x8*)(C + (rowBase + r) * N + colBase + c) = *(const u16x8*)&sm[idx];
    }
}

// ---------------------------------------------------------------------------
// GRU recurrence. Grid = 256 blocks x 256 threads.
//   bi = blockIdx.x & 15 -> batch rows [bi*16, +16); bj = blockIdx.x >> 4 ->
//   hidden cols [bj*32, +32). Whh fragment-resident in registers; K split
//   across 4 waves, partials reduced via padded LDS. 16 blocks sharing bi
//   couple step-to-step -> 16-block group barrier.
//
// FENCELESS barrier: all cross-block data moves via sc0/sc1 (LLC-coherent)
// accesses, so ordering needs only vmcnt-drain (__syncthreads emits
// s_waitcnt vmcnt(0) before s_barrier) + the LLC serialization point.
// __threadfence (= buffer_wbl2 + buffer_inv, a 4MB L2 flush per step!) was
// the 19us/step cost in round 4.
// ---------------------------------------------------------------------------
DEVI void groupbar(unsigned* wptr) {
    __syncthreads();  // drains this block's coherent stores to LLC
    if (threadIdx.x == 0) {
        __hip_atomic_fetch_add(wptr, 1u, __ATOMIC_RELAXED, __HIP_MEMORY_SCOPE_AGENT);
        while (__hip_atomic_load(wptr, __ATOMIC_RELAXED, __HIP_MEMORY_SCOPE_AGENT) < 16u)
            __builtin_amdgcn_s_sleep(1);
    }
    __syncthreads();
}

__global__ __launch_bounds__(256, 1) void gru_rec(
    const unsigned short* __restrict__ gi,   // [Tc][NB][G3] bf16 (bih folded in)
    const unsigned short* __restrict__ Whh,  // [G3][HD] bf16 (staged)
    const unsigned short* __restrict__ bhh,  // [G3] bf16 (staged)
    const float* __restrict__ keep,          // [LSEQ][NB]
    const unsigned short* __restrict__ mem,  // [NB][1024] bf16 (staged)
    unsigned short* __restrict__ hdb,        // [2][NB][HD] double buffer
    unsigned short* __restrict__ Y,          // [Tc][NB][HD] chunk-local bf16
    unsigned short* __restrict__ hnB,        // [NB][1024] bf16 out
    float* __restrict__ hnF,                 // [NB][1024] f32 out
    const unsigned* __restrict__ fdt,
    int t0, int Tc, int layerOff,
    unsigned* __restrict__ ctr) {            // (Tc+1)*16 slots, 32-word stride
    const int tid = threadIdx.x;
    const int l = tid & 63, w = tid >> 6, lr = l & 15, lq = l >> 4;
    const int bi = blockIdx.x & 15, bj = blockIdx.x >> 4;
    const bool f32out = (*fdt != 0u);

    __shared__ float red[4][16][100];  // padded stride

    // --- Whh fragments -> registers (one-time) ---
    bf16x8 wreg[6][4];
#pragma unroll
    for (int fr = 0; fr < 6; fr++) {
        int g = fr >> 1, cf = fr & 1;
        long row = (long)g * HD + bj * 32 + cf * 16 + lr;
#pragma unroll
        for (int ks = 0; ks < 4; ks++) {
            int k = w * 128 + ks * 32 + lq * 8;
            wreg[fr][ks] = *(const bf16x8*)(Whh + row * HD + k);
        }
    }

    const int m = tid >> 4, c0 = (tid & 15) * 2;
    const int n_g = bi * 16 + m;
    const int ch = bj * 32 + c0;
    float bh[3][2];
#pragma unroll
    for (int g = 0; g < 3; g++) {
        unsigned v = *(const unsigned*)(bhh + g * HD + ch);
        bh[g][0] = b2f((unsigned short)(v & 0xffffu));
        bh[g][1] = b2f((unsigned short)(v >> 16));
    }

    if (t0 == 0) {  // init h0 from memory (layer slice) into parity 0
        unsigned v = *(const unsigned*)(mem + (long)n_g * 1024 + layerOff + ch);
        cstore((unsigned*)(hdb + (long)n_g * HD + ch), v);
        groupbar(ctr + ((long)Tc * 16 + bi) * 32);
    }

    // own h patch carried in registers (bf16-rounded, consistent with what
    // other blocks read from hdb)
    float hpv[2];
    {
        unsigned hp0 = cload((const unsigned*)(hdb + (long)(t0 & 1) * NB * HD + (long)n_g * HD + ch));
        hpv[0] = b2f((unsigned short)(hp0 & 0xffffu));
        hpv[1] = b2f((unsigned short)(hp0 >> 16));
    }

    // prefetch gi/keep for first step
    unsigned gv[3];
    float kp;
    {
        const unsigned short* gp = gi + (long)n_g * G3;
#pragma unroll
        for (int g = 0; g < 3; g++) gv[g] = *(const unsigned*)(gp + g * HD + ch);
        kp = keep[(long)t0 * NB + n_g];
    }

    for (int t = t0; t < t0 + Tc; ++t) {
        const unsigned short* hc = hdb + (long)(t & 1) * NB * HD;
        unsigned short* hx = hdb + (long)((t + 1) & 1) * NB * HD;

        // coherent 16B-vector loads of the h stripe (written by other blocks)
        const unsigned* hrow = (const unsigned*)(hc + (long)(bi * 16 + lr) * HD);
        union { u32x4 u; bf16x8 v; } t0u, t1u, t2u, t3u;
        cload4x4(hrow + w * 64 + 0 * 16 + lq * 4, hrow + w * 64 + 1 * 16 + lq * 4,
                 hrow + w * 64 + 2 * 16 + lq * 4, hrow + w * 64 + 3 * 16 + lq * 4,
                 t0u.u, t1u.u, t2u.u, t3u.u);
        bf16x8 af[4] = { t0u.v, t1u.v, t2u.v, t3u.v };

        f32x4 acc[6] = {};
#pragma unroll
        for (int ks = 0; ks < 4; ks++)
#pragma unroll
            for (int fr = 0; fr < 6; fr++)
                acc[fr] = __builtin_amdgcn_mfma_f32_16x16x32_bf16(af[ks], wreg[fr][ks], acc[fr], 0, 0, 0);

#pragma unroll
        for (int fr = 0; fr < 6; fr++)
#pragma unroll
            for (int rg = 0; rg < 4; rg++)
                red[w][lq * 4 + rg][fr * 16 + lr] = acc[fr][rg];
        __syncthreads();

        float s[3][2];
#pragma unroll
        for (int g = 0; g < 3; g++) { s[g][0] = 0.f; s[g][1] = 0.f; }
#pragma unroll
        for (int ww = 0; ww < 4; ww++)
#pragma unroll
            for (int g = 0; g < 3; g++) {
                const float* p = &red[ww][m][g * 32 + c0];
                s[g][0] += p[0];
                s[g][1] += p[1];
            }

        unsigned short yo[2], ho[2];
        float hcf[2];
#pragma unroll
        for (int j = 0; j < 2; j++) {
            float ir  = b2f((unsigned short)((gv[0] >> (16 * j)) & 0xffffu));
            float iz  = b2f((unsigned short)((gv[1] >> (16 * j)) & 0xffffu));
            float in_ = b2f((unsigned short)((gv[2] >> (16 * j)) & 0xffffu));
            float r = 1.f / (1.f + __expf(-(ir + s[0][j] + bh[0][j])));
            float z = 1.f / (1.f + __expf(-(iz + s[1][j] + bh[1][j])));
            float nn = tanhf(in_ + r * (s[2][j] + bh[2][j]));
            float hnew = (1.f - z) * nn + z * hpv[j];
            hcf[j] = hnew * kp;
            yo[j] = f2b(hnew);
            ho[j] = f2b(hcf[j]);
            hpv[j] = b2f(ho[j]);  // carry bf16-rounded h*keep for next step
        }
        unsigned ypack = (unsigned)yo[0] | ((unsigned)yo[1] << 16);
        unsigned hpack = (unsigned)ho[0] | ((unsigned)ho[1] << 16);
        *(unsigned*)(Y + ((long)(t - t0) * NB + n_g) * HD + ch) = ypack;   // cross-kernel
        cstore((unsigned*)(hx + (long)n_g * HD + ch), hpack);              // cross-block
        if (t == LSEQ - 1) {
            if (f32out) {
                hnF[(long)n_g * 1024 + layerOff + ch]     = hcf[0];
                hnF[(long)n_g * 1024 + layerOff + ch + 1] = hcf[1];
            } else {
                *(unsigned*)(hnB + (long)n_g * 1024 + layerOff + ch) = hpack;
            }
        }

        if (t + 1 < t0 + Tc) {
            const unsigned short* gp = gi + ((long)(t + 1 - t0) * NB + n_g) * G3;
#pragma unroll
            for (int g = 0; g < 3; g++) gv[g] = *(const unsigned*)(gp + g * HD + ch);
            kp = keep[(long)(t + 1) * NB + n_g];
            groupbar(ctr + ((long)(t - t0) * 16 + bi) * 32);
        }
    }
}

// ---------------------------------------------------------------------------
// Host launcher — dtype-adaptive chunked two-layer pipeline.
// ---------------------------------------------------------------------------
extern "C" void kernel_launch(void* const* d_in, const int* in_sizes, int n_in,
                              void* d_out, int out_size, void* d_ws, size_t ws_size,
                              hipStream_t stream) {
    const void* x    = d_in[0];
    const void* mem  = d_in[1];
    const void* done = d_in[2];
    const void* fsrc[11] = { mem, d_in[3], d_in[4], d_in[5], d_in[6],
                             d_in[7], d_in[8], d_in[9], d_in[10], d_in[11], d_in[12] };
    const long  fn[11]   = { (long)NB * 1024, (long)G3 * CIN, (long)G3 * HD, G3, G3,
                             (long)G3 * HD, (long)G3 * HD, G3, G3, (long)NOUT * HD, NOUT };

    unsigned short* outB = (unsigned short*)d_out;
    float*          outF = (float*)d_out;
    unsigned short* hnB  = outB + (size_t)LSEQ * NB * NOUT;
    float*          hnF  = outF + (size_t)LSEQ * NB * NOUT;

    char* ws = (char*)d_ws;
    const size_t oFlag = 0;                                   // fdt @ +0, done-flag @ +64
    const size_t oKeep = 256;                                 // 0.5 MB
    const size_t oCtr  = oKeep + (size_t)LSEQ * NB * 4;       // 4 MB
    const size_t oWC   = oCtr + (size_t)4 * 1024 * 1024;      // staged weights/mem
    size_t wcTot = 0;
    size_t wcOff[11];
    for (int i = 0; i < 11; i++) { wcOff[i] = wcTot; wcTot += (size_t)fn[i] * 2; wcTot = (wcTot + 255) & ~(size_t)255; }
    const size_t oHdb0 = oWC + wcTot;
    const size_t oHdb1 = oHdb0 + (size_t)2 * NB * HD * 2;
    const size_t oDyn  = oHdb1 + (size_t)2 * NB * HD * 2;

    int Tc = 4;
    const int cand[6] = {128, 64, 32, 16, 8, 4};
    for (int i = 0; i < 6; i++) {
        size_t need = oDyn + (size_t)cand[i] * NB * (CIN + G3 + 2 * HD) * 2;
        if (need <= ws_size) { Tc = cand[i]; break; }
    }
    const size_t oXC  = oDyn;
    const size_t oGI  = oXC + (size_t)Tc * NB * CIN * 2;
    const size_t oY0c = oGI + (size_t)Tc * NB * G3 * 2;
    const size_t oY1c = oY0c + (size_t)Tc * NB * HD * 2;

    unsigned*       FDT  = (unsigned*)(ws + oFlag);
    unsigned*       DFLG = (unsigned*)(ws + oFlag + 64);
    float*          KEEP = (float*)(ws + oKeep);
    unsigned*       CTR  = (unsigned*)(ws + oCtr);
    unsigned short* WC   = (unsigned short*)(ws + oWC);
    unsigned short* HDB0 = (unsigned short*)(ws + oHdb0);
    unsigned short* HDB1 = (unsigned short*)(ws + oHdb1);
    unsigned short* XC   = (unsigned short*)(ws + oXC);
    unsigned short* GIb  = (unsigned short*)(ws + oGI);
    unsigned short* Y0c  = (unsigned short*)(ws + oY0c);
    unsigned short* Y1c  = (unsigned short*)(ws + oY1c);

    unsigned short* MEMc = WC + wcOff[0] / 2;
    unsigned short* WIH0 = WC + wcOff[1] / 2;
    unsigned short* WHH0 = WC + wcOff[2] / 2;
    unsigned short* BIH0 = WC + wcOff[3] / 2;
    unsigned short* BHH0 = WC + wcOff[4] / 2;
    unsigned short* WIH1 = WC + wcOff[5] / 2;
    unsigned short* WHH1 = WC + wcOff[6] / 2;
    unsigned short* BIH1 = WC + wcOff[7] / 2;
    unsigned short* BHH1 = WC + wcOff[8] / 2;
    unsigned short* WPc  = WC + wcOff[9] / 2;
    unsigned short* BPc  = WC + wcOff[10] / 2;

    hipMemsetAsync(ws + oCtr, 0, (size_t)4 * 1024 * 1024, stream);
    detect_fdt<<<1, 256, 0, stream>>>((const unsigned short*)x, 4096, FDT);
    detect_done<<<1, 256, 0, stream>>>((const unsigned char*)done, in_sizes[2], DFLG);
    expand_done<<<(LSEQ * NB + 255) / 256, 256, 0, stream>>>(done, DFLG, KEEP, LSEQ * NB);

    for (int i = 0; i < 11; i++) {
        int blocks = (int)((fn[i] + 1023) / 1024);
        if (blocks > 2048) blocks = 2048;
        cast_bf16<<<blocks, 256, 0, stream>>>(fsrc[i], 0, WC + wcOff[i] / 2, fn[i], FDT);
    }

    size_t ctrWords = 0;
    const size_t ctrStep = (size_t)(Tc + 1) * 16 * 32;
    for (int t0 = 0; t0 < LSEQ; t0 += Tc) {
        const long xcN = (long)Tc * NB * CIN;
        cast_bf16<<<2048, 256, 0, stream>>>(x, (long)t0 * NB * CIN, XC, xcN, FDT);
        gemm_nt<<<dim3(G3 / 128, Tc * NB / 128), 256, 0, stream>>>(
            XC, WIH0, BIH0, GIb, nullptr, nullptr, Tc * NB, G3, CIN);
        gru_rec<<<256, 256, 0, stream>>>(GIb, WHH0, BHH0, KEEP, MEMc, HDB0,
                                         Y0c, hnB, hnF, FDT, t0, Tc, 0, CTR + ctrWords);
        ctrWords += ctrStep;
        gemm_nt<<<dim3(G3 / 128, Tc * NB / 128), 256, 0, stream>>>(
            Y0c, WIH1, BIH1, GIb, nullptr, nullptr, Tc * NB, G3, HD);
        gru_rec<<<256, 256, 0, stream>>>(GIb, WHH1, BHH1, KEEP, MEMc, HDB1,
                                         Y1c, hnB, hnF, FDT, t0, Tc, HD, CTR + ctrWords);
        ctrWords += ctrStep;
        gemm_nt<<<dim3(NOUT / 128, Tc * NB / 128), 256, 0, stream>>>(
            Y1c, WPc, BPc, outB + (size_t)t0 * NB * NOUT,
            outF + (size_t)t0 * NB * NOUT, FDT, Tc * NB, NOUT, HD);
    }
}